// Round 18
// baseline (3535.015 us; speedup 1.0000x reference)
//
#include <hip/hip_runtime.h>
#include <math.h>

#define S_LEN 2048
#define BATCH 64
#define IN_D  128
#define HID   256
#define G4    1024   // 4*HID

#if defined(__has_builtin)
# if __has_builtin(__builtin_amdgcn_sdot4)
#  define USE_SDOT4 1
# endif
#endif

__device__ __forceinline__ int dot4i8(int a, int b, int c) {
#ifdef USE_SDOT4
    return __builtin_amdgcn_sdot4(a, b, c, false);
#else
    int r = c;
    r += ((a << 24) >> 24) * ((b << 24) >> 24);
    r += ((a << 16) >> 24) * ((b << 16) >> 24);
    r += ((a <<  8) >> 24) * ((b <<  8) >> 24);
    r += ( a        >> 24) * ( b        >> 24);
    return r;
#endif
}

// fake_quant value: clip(round_half_even(x*16), -128, 127)/16 — exact f32 ops
__device__ __forceinline__ float fq4(float x) {
    return fminf(fmaxf(rintf(x * 16.0f), -128.0f), 127.0f) * 0.0625f;
}

// ---------------------------------------------------------------------------
// XLA-CPU JIT exp f32 (VF32Exp, FMA host, contract ON) — bit-frozen from r14.
// ---------------------------------------------------------------------------
__device__ __forceinline__ float exp_vsl(float x) {
    const float xc = fminf(fmaxf(x, -88.3762626647949f), 88.3762626647950f);
    const float fx = floorf(fmaf(xc, 1.44269504088896341f, 0.5f));
    float r = fmaf(-fx, 0.693359375f, xc);
    r = fmaf(fx, 2.12194440e-4f, r);
    const float z = __fmul_rn(r, r);
    float y = fmaf(r, 1.9875691500e-4f, 1.3981999507e-3f);
    y = fmaf(y, r, 8.3334519073e-3f);
    y = fmaf(y, r, 4.1665795894e-2f);
    y = fmaf(y, r, 1.6666665459e-1f);
    y = fmaf(y, r, 5.0000001201e-1f);
    y = fmaf(y, z, r);
    y = __fadd_rn(y, 1.0f);
    const int n = (int)fx;
    const float sc = __int_as_float((n + 127) << 23);
    return __fmul_rn(y, sc);
}

// ---------------------------------------------------------------------------
// XLA-CPU JIT tanh f32 (VF32Tanh): clamp ±9, FMA Horner — bit-frozen from r14.
// ---------------------------------------------------------------------------
__device__ __forceinline__ float tanh_vsl(float x) {
    const float xc = fminf(fmaxf(x, -9.0f), 9.0f);
    const float x2 = __fmul_rn(xc, xc);
    float p = -2.76076847742355e-16f;
    p = fmaf(p, x2, 2.00018790482477e-13f);
    p = fmaf(p, x2, -8.60467152213735e-11f);
    p = fmaf(p, x2, 5.12229709037114e-08f);
    p = fmaf(p, x2, 1.48572235717979e-05f);
    p = fmaf(p, x2, 6.37261928875436e-04f);
    p = fmaf(p, x2, 4.89352455891786e-03f);
    p = __fmul_rn(p, xc);
    float q = 1.19825839466702e-06f;
    q = fmaf(q, x2, 1.18534705686654e-04f);
    q = fmaf(q, x2, 2.26843463243900e-03f);
    q = fmaf(q, x2, 4.89352518554385e-03f);
    return __fdiv_rn(p, q);
}

// XLA LogisticExpander: 1 / (1 + exp(-x)) — bit-frozen.
__device__ __forceinline__ float sig_vsl(float x) {
    const float ef = exp_vsl(-x);
    return __fdiv_rn(1.0f, __fadd_rn(1.0f, ef));
}

// ---------------------------------------------------------------------------
// Prep (unchanged)
// ---------------------------------------------------------------------------
__global__ void qlstm_prep(const float* __restrict__ wih, const float* __restrict__ whh,
                           const float* __restrict__ bih, const float* __restrict__ bhh,
                           float* __restrict__ wiq, int* __restrict__ whqT,
                           float* __restrict__ biq, float* __restrict__ bhq,
                           float* __restrict__ c_state, int* __restrict__ hq_state) {
    const int idx = blockIdx.x * 256 + threadIdx.x;
    if (idx < G4 * IN_D) wiq[idx] = fq4(wih[idx]);
    if (idx < (HID / 4) * G4) {
        const int d = idx >> 10;
        const int j = idx & 1023;
        int pack = 0;
#pragma unroll
        for (int c = 0; c < 4; ++c) {
            const int k = d * 4 + c;
            float q = fminf(fmaxf(rintf(whh[j * HID + k] * 16.0f), -128.0f), 127.0f);
            int qi = (int)q;
            pack |= (qi & 0xff) << (8 * c);
        }
        whqT[idx] = pack;
    }
    if (idx < G4) { biq[idx] = fq4(bih[idx]); bhq[idx] = fq4(bhh[idx]); }
    if (idx < BATCH * HID) c_state[idx] = 0.0f;
    if (idx < BATCH * (HID / 4)) hq_state[idx] = 0;
}

// ---------------------------------------------------------------------------
// GEMM: UNFUSED acc = add(acc, mul(a,b)) ascending k (bit-frozen from r14).
// ---------------------------------------------------------------------------
#define GPAD 132
__global__ __launch_bounds__(256, 1) void qlstm_gx(
    const float* __restrict__ X, const float* __restrict__ Wq,
    const float* __restrict__ biq, float* __restrict__ Gx, int Mc) {
    __shared__ float Xs[IN_D][GPAD];
    __shared__ float Ws[IN_D][GPAD];
    const int t  = threadIdx.x;
    const int m0 = blockIdx.x * 128;
    const int n0 = blockIdx.y * 128;

#pragma unroll
    for (int i = 0; i < 16; ++i) {
        const int flat = i * 256 + t;
        const int m  = flat >> 5;
        const int k4 = flat & 31;
        float4 v = make_float4(0.f, 0.f, 0.f, 0.f);
        if (m0 + m < Mc) v = *(const float4*)(X + (size_t)(m0 + m) * IN_D + k4 * 4);
        Xs[k4 * 4 + 0][m] = v.x; Xs[k4 * 4 + 1][m] = v.y;
        Xs[k4 * 4 + 2][m] = v.z; Xs[k4 * 4 + 3][m] = v.w;
        float4 w = *(const float4*)(Wq + (size_t)(n0 + m) * IN_D + k4 * 4);
        Ws[k4 * 4 + 0][m] = w.x; Ws[k4 * 4 + 1][m] = w.y;
        Ws[k4 * 4 + 2][m] = w.z; Ws[k4 * 4 + 3][m] = w.w;
    }
    __syncthreads();

    const int tx = t & 15, ty = t >> 4;
    float acc[8][8];
#pragma unroll
    for (int i = 0; i < 8; ++i)
#pragma unroll
        for (int j = 0; j < 8; ++j) acc[i][j] = 0.0f;

#pragma unroll 4
    for (int k = 0; k < IN_D; ++k) {
        float4 a0 = *(const float4*)&Xs[k][ty * 8];
        float4 a1 = *(const float4*)&Xs[k][ty * 8 + 4];
        float4 b0 = *(const float4*)&Ws[k][tx * 8];
        float4 b1 = *(const float4*)&Ws[k][tx * 8 + 4];
        const float a[8]  = {a0.x, a0.y, a0.z, a0.w, a1.x, a1.y, a1.z, a1.w};
        const float bb[8] = {b0.x, b0.y, b0.z, b0.w, b1.x, b1.y, b1.z, b1.w};
#pragma unroll
        for (int i = 0; i < 8; ++i)
#pragma unroll
            for (int j = 0; j < 8; ++j)
                acc[i][j] = __fadd_rn(acc[i][j], __fmul_rn(a[i], bb[j]));   // UNFUSED
    }

    float4 bv0 = *(const float4*)(biq + n0 + tx * 8);
    float4 bv1 = *(const float4*)(biq + n0 + tx * 8 + 4);
    const float bb[8] = {bv0.x, bv0.y, bv0.z, bv0.w, bv1.x, bv1.y, bv1.z, bv1.w};
#pragma unroll
    for (int i = 0; i < 8; ++i) {
        const int m = m0 + ty * 8 + i;
        if (m < Mc) {
            float o[8];
#pragma unroll
            for (int j = 0; j < 8; ++j) o[j] = __fadd_rn(acc[i][j], bb[j]);
            *(float4*)(Gx + (size_t)m * G4 + n0 + tx * 8)     = make_float4(o[0], o[1], o[2], o[3]);
            *(float4*)(Gx + (size_t)m * G4 + n0 + tx * 8 + 4) = make_float4(o[4], o[5], o[6], o[7]);
        }
    }
}

// ---------------------------------------------------------------------------
// Scan, 1024 threads/block, one gate row per thread.
// Weights: k-groups 0..47 pinned in VGPRs via non-rematerializable v_mov asm;
// k-groups 48..63 staged once in LDS (64KB), read per step as 4 ds_read_b128
// with per-lane slot rotation (integer dot regrouping exact).
// All f32 arithmetic bit-identical to the passing r14 stack.
// ---------------------------------------------------------------------------
__global__ __launch_bounds__(1024) void qlstm_scan(
    const float* __restrict__ Gx, const int* __restrict__ whqT,
    const float* __restrict__ bhq,
    float* __restrict__ out, float* __restrict__ c_state, int* __restrict__ hq_state,
    float* __restrict__ hn, float* __restrict__ cn, int s0, int CHc) {
    const int b = blockIdx.x;
    const int t = threadIdx.x;

    __shared__ __align__(16) int wlds[G4 * 16]; // 64KB: k-groups 48..63, [row][16]
    __shared__ __align__(16) int hq[2][64];     // packed int8 fq(h)*16, dbuf
    __shared__ float gl[G4];                    // transformed gates

    // stage LDS weights (row t, dwords j=0..15 <- k-groups 48+j), coalesced per j
#pragma unroll
    for (int j = 0; j < 16; ++j) wlds[t * 16 + j] = whqT[(48 + j) * G4 + t];

    // 48 VGPR-pinned weights: k-groups 0..47
    int w[48];
#pragma unroll
    for (int d = 0; d < 48; ++d) w[d] = whqT[d * G4 + t];
#pragma unroll
    for (int d = 0; d < 48; ++d)
        asm volatile("v_mov_b32 %0, %1" : "=v"(w[d]) : "v"(w[d]));  // non-remat pin

    const float bh = bhq[t];

    float creg = 0.0f;
    if (t < HID) creg = c_state[b * HID + t];
    if (t < 64)  hq[0][t] = hq_state[b * 64 + t];
    __syncthreads();

    float gx = Gx[(size_t)b * G4 + t];
    const int rot = (t >> 1) & 3;               // LDS slot rotation (bank spread)

    for (int sl = 0; sl < CHc; ++sl) {
        const int p = sl & 1;
        float nx = 0.0f;
        if (sl + 1 < CHc) nx = Gx[(size_t)((sl + 1) * BATCH + b) * G4 + t];

        // ---- hh matvec row t: 4 independent chains (integer-exact) ----
        int ca0 = 0, ca1 = 0, ca2 = 0, ca3 = 0;
#pragma unroll
        for (int d = 0; d < 4; ++d) {
            const int4 h0 = ((const int4*)hq[p])[d];        // broadcast reads
            const int4 h1 = ((const int4*)hq[p])[4 + d];
            const int4 h2 = ((const int4*)hq[p])[8 + d];
            ca0 = dot4i8(w[d * 4 + 0], h0.x, ca0);
            ca0 = dot4i8(w[d * 4 + 1], h0.y, ca0);
            ca0 = dot4i8(w[d * 4 + 2], h0.z, ca0);
            ca0 = dot4i8(w[d * 4 + 3], h0.w, ca0);
            ca1 = dot4i8(w[16 + d * 4 + 0], h1.x, ca1);
            ca1 = dot4i8(w[16 + d * 4 + 1], h1.y, ca1);
            ca1 = dot4i8(w[16 + d * 4 + 2], h1.z, ca1);
            ca1 = dot4i8(w[16 + d * 4 + 3], h1.w, ca1);
            ca2 = dot4i8(w[32 + d * 4 + 0], h2.x, ca2);
            ca2 = dot4i8(w[32 + d * 4 + 1], h2.y, ca2);
            ca2 = dot4i8(w[32 + d * 4 + 2], h2.z, ca2);
            ca2 = dot4i8(w[32 + d * 4 + 3], h2.w, ca2);
        }
        // k-groups 48..63 from LDS, rotated slots (4x ds_read_b128)
#pragma unroll
        for (int s = 0; s < 4; ++s) {
            const int sp = (s + rot) & 3;
            const int4 wv = *((const int4*)&wlds[t * 16 + sp * 4]);
            const int hbase = 48 + sp * 4;
            const int* hqw = (const int*)hq[p];
            ca3 = dot4i8(wv.x, hqw[hbase + 0], ca3);
            ca3 = dot4i8(wv.y, hqw[hbase + 1], ca3);
            ca3 = dot4i8(wv.z, hqw[hbase + 2], ca3);
            ca3 = dot4i8(wv.w, hqw[hbase + 3], ca3);
        }
        const int acc = (ca0 + ca1) + (ca2 + ca3);

        const float hh = (float)acc * 0.00390625f;         // exact multiple of 2^-8
        const float gate = __fadd_rn(__fadd_rn(gx, hh), bh);

        float tv;                                          // wave-uniform branches
        if (t < 512)       tv = sig_vsl(gate);             // i rows, f rows
        else if (t < 768)  tv = tanh_vsl(gate);            // g rows
        else               tv = sig_vsl(gate);             // o rows
        gl[t] = tv;
        __syncthreads();

        if (t < HID) {
            const float fv = gl[t + 256];
            const float gv = gl[t + 512];
            const float ov = gl[t + 768];
            const float cq = fminf(fmaxf(rintf(__fmul_rn(creg, 16.0f)), -128.0f), 127.0f) * 0.0625f;
            const float c1 = fmaf(fv, cq, __fmul_rn(tv, gv));   // contracted (r14)
            const float h1 = __fmul_rn(ov, tanh_vsl(c1));
            creg = c1;
            out[(size_t)((s0 + sl) * BATCH + b) * HID + t] = h1;
            const int hb = (int)fminf(fmaxf(rintf(__fmul_rn(h1, 16.0f)), -128.0f), 127.0f);
            ((signed char*)hq[p ^ 1])[t] = (signed char)hb;
            if (s0 + sl == S_LEN - 1) {
                hn[b * HID + t] = h1;
                cn[b * HID + t] = c1;
            }
        }
        __syncthreads();
        gx = nx;
    }

    if (t < 64)  hq_state[b * 64 + t] = hq[CHc & 1][t];
    if (t < HID) c_state[b * HID + t] = creg;
}

// ---------------------------------------------------------------------------
// Host side (unchanged)
// ---------------------------------------------------------------------------
extern "C" void kernel_launch(void* const* d_in, const int* in_sizes, int n_in,
                              void* d_out, int out_size, void* d_ws, size_t ws_size,
                              hipStream_t stream) {
    (void)in_sizes; (void)n_in; (void)out_size;
    const float* x   = (const float*)d_in[0];
    const float* wih = (const float*)d_in[1];
    const float* whh = (const float*)d_in[2];
    const float* bih = (const float*)d_in[3];
    const float* bhh = (const float*)d_in[4];

    float* out = (float*)d_out;
    float* hn  = out + (size_t)S_LEN * BATCH * HID;
    float* cn  = hn + (size_t)BATCH * HID;

    char* ws = (char*)d_ws;
    const size_t off_wiq  = 0;
    const size_t off_whqT = off_wiq  + 524288;
    const size_t off_biq  = off_whqT + 262144;
    const size_t off_bhq  = off_biq  + 4096;
    const size_t off_c    = off_bhq  + 4096;
    const size_t off_hq   = off_c    + 65536;
    const size_t off_gx   = off_hq   + 16384;

    float* wiq     = (float*)(ws + off_wiq);
    int*   whqT    = (int*)  (ws + off_whqT);
    float* biq     = (float*)(ws + off_biq);
    float* bhq     = (float*)(ws + off_bhq);
    float* c_state = (float*)(ws + off_c);
    int*   hq_st   = (int*)  (ws + off_hq);
    float* gx      = (float*)(ws + off_gx);

    const size_t per_step = (size_t)BATCH * G4 * 4;
    size_t avail = (ws_size > off_gx) ? (ws_size - off_gx) : 0;
    int CH = (int)(avail / per_step);
    if (CH > S_LEN) CH = S_LEN;
    if (CH < 1) CH = 1;

    qlstm_prep<<<512, 256, 0, stream>>>(wih, whh, bih, bhh, wiq, whqT, biq, bhq, c_state, hq_st);

    for (int s0 = 0; s0 < S_LEN; s0 += CH) {
        const int CHc = (S_LEN - s0 < CH) ? (S_LEN - s0) : CH;
        const int Mc  = CHc * BATCH;
        dim3 grid((Mc + 127) / 128, G4 / 128);
        qlstm_gx<<<grid, 256, 0, stream>>>(x + (size_t)s0 * BATCH * IN_D, wiq, biq, gx, Mc);
        qlstm_scan<<<64, 1024, 0, stream>>>(gx, whqT, bhq, out, c_state, hq_st, hn, cn, s0, CHc);
    }
}

// Round 19
// 3214.684 us; speedup vs baseline: 1.0996x; 1.0996x over previous
//
#include <hip/hip_runtime.h>
#include <math.h>

#define S_LEN 2048
#define BATCH 64
#define IN_D  128
#define HID   256
#define G4    1024   // 4*HID

#if defined(__has_builtin)
# if __has_builtin(__builtin_amdgcn_sdot4)
#  define USE_SDOT4 1
# endif
#endif

__device__ __forceinline__ int dot4i8(int a, int b, int c) {
#ifdef USE_SDOT4
    return __builtin_amdgcn_sdot4(a, b, c, false);
#else
    int r = c;
    r += ((a << 24) >> 24) * ((b << 24) >> 24);
    r += ((a << 16) >> 24) * ((b << 16) >> 24);
    r += ((a <<  8) >> 24) * ((b <<  8) >> 24);
    r += ( a        >> 24) * ( b        >> 24);
    return r;
#endif
}

// fake_quant value: clip(round_half_even(x*16), -128, 127)/16 — exact f32 ops
__device__ __forceinline__ float fq4(float x) {
    return fminf(fmaxf(rintf(x * 16.0f), -128.0f), 127.0f) * 0.0625f;
}

// ---------------------------------------------------------------------------
// XLA-CPU JIT exp f32 (VF32Exp, FMA host, contract ON) — bit-frozen from r14.
// ---------------------------------------------------------------------------
__device__ __forceinline__ float exp_vsl(float x) {
    const float xc = fminf(fmaxf(x, -88.3762626647949f), 88.3762626647950f);
    const float fx = floorf(fmaf(xc, 1.44269504088896341f, 0.5f));
    float r = fmaf(-fx, 0.693359375f, xc);
    r = fmaf(fx, 2.12194440e-4f, r);
    const float z = __fmul_rn(r, r);
    float y = fmaf(r, 1.9875691500e-4f, 1.3981999507e-3f);
    y = fmaf(y, r, 8.3334519073e-3f);
    y = fmaf(y, r, 4.1665795894e-2f);
    y = fmaf(y, r, 1.6666665459e-1f);
    y = fmaf(y, r, 5.0000001201e-1f);
    y = fmaf(y, z, r);
    y = __fadd_rn(y, 1.0f);
    const int n = (int)fx;
    const float sc = __int_as_float((n + 127) << 23);
    return __fmul_rn(y, sc);
}

// ---------------------------------------------------------------------------
// XLA-CPU JIT tanh f32 (VF32Tanh): clamp ±9, FMA Horner — bit-frozen from r14.
// ---------------------------------------------------------------------------
__device__ __forceinline__ float tanh_vsl(float x) {
    const float xc = fminf(fmaxf(x, -9.0f), 9.0f);
    const float x2 = __fmul_rn(xc, xc);
    float p = -2.76076847742355e-16f;
    p = fmaf(p, x2, 2.00018790482477e-13f);
    p = fmaf(p, x2, -8.60467152213735e-11f);
    p = fmaf(p, x2, 5.12229709037114e-08f);
    p = fmaf(p, x2, 1.48572235717979e-05f);
    p = fmaf(p, x2, 6.37261928875436e-04f);
    p = fmaf(p, x2, 4.89352455891786e-03f);
    p = __fmul_rn(p, xc);
    float q = 1.19825839466702e-06f;
    q = fmaf(q, x2, 1.18534705686654e-04f);
    q = fmaf(q, x2, 2.26843463243900e-03f);
    q = fmaf(q, x2, 4.89352518554385e-03f);
    return __fdiv_rn(p, q);
}

// XLA LogisticExpander: 1 / (1 + exp(-x)) — bit-frozen.
__device__ __forceinline__ float sig_vsl(float x) {
    const float ef = exp_vsl(-x);
    return __fdiv_rn(1.0f, __fadd_rn(1.0f, ef));
}

// ---------------------------------------------------------------------------
// Prep (unchanged)
// ---------------------------------------------------------------------------
__global__ void qlstm_prep(const float* __restrict__ wih, const float* __restrict__ whh,
                           const float* __restrict__ bih, const float* __restrict__ bhh,
                           float* __restrict__ wiq, int* __restrict__ whqT,
                           float* __restrict__ biq, float* __restrict__ bhq,
                           float* __restrict__ c_state, int* __restrict__ hq_state) {
    const int idx = blockIdx.x * 256 + threadIdx.x;
    if (idx < G4 * IN_D) wiq[idx] = fq4(wih[idx]);
    if (idx < (HID / 4) * G4) {
        const int d = idx >> 10;
        const int j = idx & 1023;
        int pack = 0;
#pragma unroll
        for (int c = 0; c < 4; ++c) {
            const int k = d * 4 + c;
            float q = fminf(fmaxf(rintf(whh[j * HID + k] * 16.0f), -128.0f), 127.0f);
            int qi = (int)q;
            pack |= (qi & 0xff) << (8 * c);
        }
        whqT[idx] = pack;
    }
    if (idx < G4) { biq[idx] = fq4(bih[idx]); bhq[idx] = fq4(bhh[idx]); }
    if (idx < BATCH * HID) c_state[idx] = 0.0f;
    if (idx < BATCH * (HID / 4)) hq_state[idx] = 0;
}

// ---------------------------------------------------------------------------
// GEMM: UNFUSED acc = add(acc, mul(a,b)) ascending k (bit-frozen from r14).
// ---------------------------------------------------------------------------
#define GPAD 132
__global__ __launch_bounds__(256, 1) void qlstm_gx(
    const float* __restrict__ X, const float* __restrict__ Wq,
    const float* __restrict__ biq, float* __restrict__ Gx, int Mc) {
    __shared__ float Xs[IN_D][GPAD];
    __shared__ float Ws[IN_D][GPAD];
    const int t  = threadIdx.x;
    const int m0 = blockIdx.x * 128;
    const int n0 = blockIdx.y * 128;

#pragma unroll
    for (int i = 0; i < 16; ++i) {
        const int flat = i * 256 + t;
        const int m  = flat >> 5;
        const int k4 = flat & 31;
        float4 v = make_float4(0.f, 0.f, 0.f, 0.f);
        if (m0 + m < Mc) v = *(const float4*)(X + (size_t)(m0 + m) * IN_D + k4 * 4);
        Xs[k4 * 4 + 0][m] = v.x; Xs[k4 * 4 + 1][m] = v.y;
        Xs[k4 * 4 + 2][m] = v.z; Xs[k4 * 4 + 3][m] = v.w;
        float4 w = *(const float4*)(Wq + (size_t)(n0 + m) * IN_D + k4 * 4);
        Ws[k4 * 4 + 0][m] = w.x; Ws[k4 * 4 + 1][m] = w.y;
        Ws[k4 * 4 + 2][m] = w.z; Ws[k4 * 4 + 3][m] = w.w;
    }
    __syncthreads();

    const int tx = t & 15, ty = t >> 4;
    float acc[8][8];
#pragma unroll
    for (int i = 0; i < 8; ++i)
#pragma unroll
        for (int j = 0; j < 8; ++j) acc[i][j] = 0.0f;

#pragma unroll 4
    for (int k = 0; k < IN_D; ++k) {
        float4 a0 = *(const float4*)&Xs[k][ty * 8];
        float4 a1 = *(const float4*)&Xs[k][ty * 8 + 4];
        float4 b0 = *(const float4*)&Ws[k][tx * 8];
        float4 b1 = *(const float4*)&Ws[k][tx * 8 + 4];
        const float a[8]  = {a0.x, a0.y, a0.z, a0.w, a1.x, a1.y, a1.z, a1.w};
        const float bb[8] = {b0.x, b0.y, b0.z, b0.w, b1.x, b1.y, b1.z, b1.w};
#pragma unroll
        for (int i = 0; i < 8; ++i)
#pragma unroll
            for (int j = 0; j < 8; ++j)
                acc[i][j] = __fadd_rn(acc[i][j], __fmul_rn(a[i], bb[j]));   // UNFUSED
    }

    float4 bv0 = *(const float4*)(biq + n0 + tx * 8);
    float4 bv1 = *(const float4*)(biq + n0 + tx * 8 + 4);
    const float bb[8] = {bv0.x, bv0.y, bv0.z, bv0.w, bv1.x, bv1.y, bv1.z, bv1.w};
#pragma unroll
    for (int i = 0; i < 8; ++i) {
        const int m = m0 + ty * 8 + i;
        if (m < Mc) {
            float o[8];
#pragma unroll
            for (int j = 0; j < 8; ++j) o[j] = __fadd_rn(acc[i][j], bb[j]);
            *(float4*)(Gx + (size_t)m * G4 + n0 + tx * 8)     = make_float4(o[0], o[1], o[2], o[3]);
            *(float4*)(Gx + (size_t)m * G4 + n0 + tx * 8 + 4) = make_float4(o[4], o[5], o[6], o[7]);
        }
    }
}

// ---------------------------------------------------------------------------
// Scan, 1024 threads/block, ONE gate row per thread.
// waves_per_eu(4,4): accept 4 waves/SIMD (1 block/CU) -> 128-VGPR budget, so
// the allocator can keep all 64 weight dwords register-resident.
// Weights loaded via VOLATILE pointer: loads cannot be rematerialized/sunk
// into the loop. All f32 arithmetic bit-identical to the passing r14 stack.
// ---------------------------------------------------------------------------
__attribute__((amdgpu_waves_per_eu(4, 4)))
__global__ __launch_bounds__(1024) void qlstm_scan(
    const float* __restrict__ Gx, const int* __restrict__ whqT,
    const float* __restrict__ bhq,
    float* __restrict__ out, float* __restrict__ c_state, int* __restrict__ hq_state,
    float* __restrict__ hn, float* __restrict__ cn, int s0, int CHc) {
    const int b = blockIdx.x;
    const int t = threadIdx.x;

    __shared__ __align__(16) int hq[2][64];   // packed int8 fq(h)*16, double buffered
    __shared__ float gl[G4];                  // transformed gates (sig/tanh applied)

    // Volatile loads: performed exactly once, values must stay live.
    const volatile int* __restrict__ wvp = whqT;
    int w[64];
#pragma unroll
    for (int d = 0; d < 64; ++d) w[d] = wvp[d * G4 + t];

    const float bh = bhq[t];

    float creg = 0.0f;
    if (t < HID) creg = c_state[b * HID + t];
    if (t < 64)  hq[0][t] = hq_state[b * 64 + t];
    __syncthreads();

    float gx = Gx[(size_t)b * G4 + t];

    for (int sl = 0; sl < CHc; ++sl) {
        const int p = sl & 1;
        float nx = 0.0f;
        if (sl + 1 < CHc) nx = Gx[(size_t)((sl + 1) * BATCH + b) * G4 + t];

        // hh matvec row t: 4 independent chains (integer-exact regrouping)
        int ca0 = 0, ca1 = 0, ca2 = 0, ca3 = 0;
#pragma unroll
        for (int d = 0; d < 4; ++d) {
            const int4 h0 = ((const int4*)hq[p])[d];        // broadcast reads
            const int4 h1 = ((const int4*)hq[p])[4 + d];
            const int4 h2 = ((const int4*)hq[p])[8 + d];
            const int4 h3 = ((const int4*)hq[p])[12 + d];
            ca0 = dot4i8(w[d * 4 + 0], h0.x, ca0);
            ca0 = dot4i8(w[d * 4 + 1], h0.y, ca0);
            ca0 = dot4i8(w[d * 4 + 2], h0.z, ca0);
            ca0 = dot4i8(w[d * 4 + 3], h0.w, ca0);
            ca1 = dot4i8(w[16 + d * 4 + 0], h1.x, ca1);
            ca1 = dot4i8(w[16 + d * 4 + 1], h1.y, ca1);
            ca1 = dot4i8(w[16 + d * 4 + 2], h1.z, ca1);
            ca1 = dot4i8(w[16 + d * 4 + 3], h1.w, ca1);
            ca2 = dot4i8(w[32 + d * 4 + 0], h2.x, ca2);
            ca2 = dot4i8(w[32 + d * 4 + 1], h2.y, ca2);
            ca2 = dot4i8(w[32 + d * 4 + 2], h2.z, ca2);
            ca2 = dot4i8(w[32 + d * 4 + 3], h2.w, ca2);
            ca3 = dot4i8(w[48 + d * 4 + 0], h3.x, ca3);
            ca3 = dot4i8(w[48 + d * 4 + 1], h3.y, ca3);
            ca3 = dot4i8(w[48 + d * 4 + 2], h3.z, ca3);
            ca3 = dot4i8(w[48 + d * 4 + 3], h3.w, ca3);
        }
        const int acc = (ca0 + ca1) + (ca2 + ca3);

        const float hh = (float)acc * 0.00390625f;         // exact multiple of 2^-8
        const float gate = __fadd_rn(__fadd_rn(gx, hh), bh);

        float tv;                                          // wave-uniform branches
        if (t < 512)       tv = sig_vsl(gate);             // i rows, f rows
        else if (t < 768)  tv = tanh_vsl(gate);            // g rows
        else               tv = sig_vsl(gate);             // o rows
        gl[t] = tv;
        __syncthreads();

        if (t < HID) {
            const float fv = gl[t + 256];
            const float gv = gl[t + 512];
            const float ov = gl[t + 768];
            const float cq = fminf(fmaxf(rintf(__fmul_rn(creg, 16.0f)), -128.0f), 127.0f) * 0.0625f;
            const float c1 = fmaf(fv, cq, __fmul_rn(tv, gv));   // contracted (r14)
            const float h1 = __fmul_rn(ov, tanh_vsl(c1));
            creg = c1;
            out[(size_t)((s0 + sl) * BATCH + b) * HID + t] = h1;
            const int hb = (int)fminf(fmaxf(rintf(__fmul_rn(h1, 16.0f)), -128.0f), 127.0f);
            ((signed char*)hq[p ^ 1])[t] = (signed char)hb;
            if (s0 + sl == S_LEN - 1) {
                hn[b * HID + t] = h1;
                cn[b * HID + t] = c1;
            }
        }
        __syncthreads();
        gx = nx;
    }

    if (t < 64)  hq_state[b * 64 + t] = hq[CHc & 1][t];
    if (t < HID) c_state[b * HID + t] = creg;
}

// ---------------------------------------------------------------------------
// Host side (unchanged)
// ---------------------------------------------------------------------------
extern "C" void kernel_launch(void* const* d_in, const int* in_sizes, int n_in,
                              void* d_out, int out_size, void* d_ws, size_t ws_size,
                              hipStream_t stream) {
    (void)in_sizes; (void)n_in; (void)out_size;
    const float* x   = (const float*)d_in[0];
    const float* wih = (const float*)d_in[1];
    const float* whh = (const float*)d_in[2];
    const float* bih = (const float*)d_in[3];
    const float* bhh = (const float*)d_in[4];

    float* out = (float*)d_out;
    float* hn  = out + (size_t)S_LEN * BATCH * HID;
    float* cn  = hn + (size_t)BATCH * HID;

    char* ws = (char*)d_ws;
    const size_t off_wiq  = 0;
    const size_t off_whqT = off_wiq  + 524288;
    const size_t off_biq  = off_whqT + 262144;
    const size_t off_bhq  = off_biq  + 4096;
    const size_t off_c    = off_bhq  + 4096;
    const size_t off_hq   = off_c    + 65536;
    const size_t off_gx   = off_hq   + 16384;

    float* wiq     = (float*)(ws + off_wiq);
    int*   whqT    = (int*)  (ws + off_whqT);
    float* biq     = (float*)(ws + off_biq);
    float* bhq     = (float*)(ws + off_bhq);
    float* c_state = (float*)(ws + off_c);
    int*   hq_st   = (int*)  (ws + off_hq);
    float* gx      = (float*)(ws + off_gx);

    const size_t per_step = (size_t)BATCH * G4 * 4;
    size_t avail = (ws_size > off_gx) ? (ws_size - off_gx) : 0;
    int CH = (int)(avail / per_step);
    if (CH > S_LEN) CH = S_LEN;
    if (CH < 1) CH = 1;

    qlstm_prep<<<512, 256, 0, stream>>>(wih, whh, bih, bhh, wiq, whqT, biq, bhq, c_state, hq_st);

    for (int s0 = 0; s0 < S_LEN; s0 += CH) {
        const int CHc = (S_LEN - s0 < CH) ? (S_LEN - s0) : CH;
        const int Mc  = CHc * BATCH;
        dim3 grid((Mc + 127) / 128, G4 / 128);
        qlstm_gx<<<grid, 256, 0, stream>>>(x + (size_t)s0 * BATCH * IN_D, wiq, biq, gx, Mc);
        qlstm_scan<<<64, 1024, 0, stream>>>(gx, whqT, bhq, out, c_state, hq_st, hn, cn, s0, CHc);
    }
}

// Round 20
// 2687.880 us; speedup vs baseline: 1.3152x; 1.1960x over previous
//
#include <hip/hip_runtime.h>
#include <math.h>

#define S_LEN 2048
#define BATCH 64
#define IN_D  128
#define HID   256
#define G4    1024   // 4*HID

#if defined(__has_builtin)
# if __has_builtin(__builtin_amdgcn_sdot4)
#  define USE_SDOT4 1
# endif
#endif

__device__ __forceinline__ int dot4i8(int a, int b, int c) {
#ifdef USE_SDOT4
    return __builtin_amdgcn_sdot4(a, b, c, false);
#else
    int r = c;
    r += ((a << 24) >> 24) * ((b << 24) >> 24);
    r += ((a << 16) >> 24) * ((b << 16) >> 24);
    r += ((a <<  8) >> 24) * ((b <<  8) >> 24);
    r += ( a        >> 24) * ( b        >> 24);
    return r;
#endif
}

// fake_quant value: clip(round_half_even(x*16), -128, 127)/16 — exact f32 ops
__device__ __forceinline__ float fq4(float x) {
    return fminf(fmaxf(rintf(x * 16.0f), -128.0f), 127.0f) * 0.0625f;
}

// ---------------------------------------------------------------------------
// XLA-CPU JIT exp f32 (VF32Exp, FMA host, contract ON) — bit-frozen from r14.
// ---------------------------------------------------------------------------
__device__ __forceinline__ float exp_vsl(float x) {
    const float xc = fminf(fmaxf(x, -88.3762626647949f), 88.3762626647950f);
    const float fx = floorf(fmaf(xc, 1.44269504088896341f, 0.5f));
    float r = fmaf(-fx, 0.693359375f, xc);
    r = fmaf(fx, 2.12194440e-4f, r);
    const float z = __fmul_rn(r, r);
    float y = fmaf(r, 1.9875691500e-4f, 1.3981999507e-3f);
    y = fmaf(y, r, 8.3334519073e-3f);
    y = fmaf(y, r, 4.1665795894e-2f);
    y = fmaf(y, r, 1.6666665459e-1f);
    y = fmaf(y, r, 5.0000001201e-1f);
    y = fmaf(y, z, r);
    y = __fadd_rn(y, 1.0f);
    const int n = (int)fx;
    const float sc = __int_as_float((n + 127) << 23);
    return __fmul_rn(y, sc);
}

// ---------------------------------------------------------------------------
// XLA-CPU JIT tanh f32 (VF32Tanh): clamp ±9, FMA Horner — bit-frozen from r14.
// ---------------------------------------------------------------------------
__device__ __forceinline__ float tanh_vsl(float x) {
    const float xc = fminf(fmaxf(x, -9.0f), 9.0f);
    const float x2 = __fmul_rn(xc, xc);
    float p = -2.76076847742355e-16f;
    p = fmaf(p, x2, 2.00018790482477e-13f);
    p = fmaf(p, x2, -8.60467152213735e-11f);
    p = fmaf(p, x2, 5.12229709037114e-08f);
    p = fmaf(p, x2, 1.48572235717979e-05f);
    p = fmaf(p, x2, 6.37261928875436e-04f);
    p = fmaf(p, x2, 4.89352455891786e-03f);
    p = __fmul_rn(p, xc);
    float q = 1.19825839466702e-06f;
    q = fmaf(q, x2, 1.18534705686654e-04f);
    q = fmaf(q, x2, 2.26843463243900e-03f);
    q = fmaf(q, x2, 4.89352518554385e-03f);
    return __fdiv_rn(p, q);
}

// XLA LogisticExpander: 1 / (1 + exp(-x)) — bit-frozen.
__device__ __forceinline__ float sig_vsl(float x) {
    const float ef = exp_vsl(-x);
    return __fdiv_rn(1.0f, __fadd_rn(1.0f, ef));
}

// ---------------------------------------------------------------------------
// Prep: wi -> fq fp32; wh -> int8 packed, per-thread-contiguous int4 layout
// whq4[(d>>2)*4096 + row*4 + (d&3)]; biases; zero state.
// ---------------------------------------------------------------------------
__global__ void qlstm_prep(const float* __restrict__ wih, const float* __restrict__ whh,
                           const float* __restrict__ bih, const float* __restrict__ bhh,
                           float* __restrict__ wiq, int* __restrict__ whq4,
                           float* __restrict__ biq, float* __restrict__ bhq,
                           float* __restrict__ c_state, int* __restrict__ hq_state) {
    const int idx = blockIdx.x * 256 + threadIdx.x;
    if (idx < G4 * IN_D) wiq[idx] = fq4(wih[idx]);
    if (idx < (HID / 4) * G4) {
        const int d = idx >> 10;         // k-group 0..63
        const int j = idx & 1023;        // gate row
        int pack = 0;
#pragma unroll
        for (int c = 0; c < 4; ++c) {
            const int k = d * 4 + c;
            float q = fminf(fmaxf(rintf(whh[j * HID + k] * 16.0f), -128.0f), 127.0f);
            int qi = (int)q;
            pack |= (qi & 0xff) << (8 * c);
        }
        whq4[(d >> 2) * 4096 + j * 4 + (d & 3)] = pack;
    }
    if (idx < G4) { biq[idx] = fq4(bih[idx]); bhq[idx] = fq4(bhh[idx]); }
    if (idx < BATCH * HID) c_state[idx] = 0.0f;
    if (idx < BATCH * (HID / 4)) hq_state[idx] = 0;
}

// ---------------------------------------------------------------------------
// Standalone GEMM (prologue, chunk 0): UNFUSED acc=add(acc,mul) ascending k.
// Bit-frozen from r14.
// ---------------------------------------------------------------------------
#define GPAD 132
__global__ __launch_bounds__(256, 1) void qlstm_gx(
    const float* __restrict__ X, const float* __restrict__ Wq,
    const float* __restrict__ biq, float* __restrict__ Gx, int Mc) {
    __shared__ float Xs[IN_D][GPAD];
    __shared__ float Ws[IN_D][GPAD];
    const int t  = threadIdx.x;
    const int m0 = blockIdx.x * 128;
    const int n0 = blockIdx.y * 128;

#pragma unroll
    for (int i = 0; i < 16; ++i) {
        const int flat = i * 256 + t;
        const int m  = flat >> 5;
        const int k4 = flat & 31;
        float4 v = make_float4(0.f, 0.f, 0.f, 0.f);
        if (m0 + m < Mc) v = *(const float4*)(X + (size_t)(m0 + m) * IN_D + k4 * 4);
        Xs[k4 * 4 + 0][m] = v.x; Xs[k4 * 4 + 1][m] = v.y;
        Xs[k4 * 4 + 2][m] = v.z; Xs[k4 * 4 + 3][m] = v.w;
        float4 w = *(const float4*)(Wq + (size_t)(n0 + m) * IN_D + k4 * 4);
        Ws[k4 * 4 + 0][m] = w.x; Ws[k4 * 4 + 1][m] = w.y;
        Ws[k4 * 4 + 2][m] = w.z; Ws[k4 * 4 + 3][m] = w.w;
    }
    __syncthreads();

    const int tx = t & 15, ty = t >> 4;
    float acc[8][8];
#pragma unroll
    for (int i = 0; i < 8; ++i)
#pragma unroll
        for (int j = 0; j < 8; ++j) acc[i][j] = 0.0f;

#pragma unroll 4
    for (int k = 0; k < IN_D; ++k) {
        float4 a0 = *(const float4*)&Xs[k][ty * 8];
        float4 a1 = *(const float4*)&Xs[k][ty * 8 + 4];
        float4 b0 = *(const float4*)&Ws[k][tx * 8];
        float4 b1 = *(const float4*)&Ws[k][tx * 8 + 4];
        const float a[8]  = {a0.x, a0.y, a0.z, a0.w, a1.x, a1.y, a1.z, a1.w};
        const float bb[8] = {b0.x, b0.y, b0.z, b0.w, b1.x, b1.y, b1.z, b1.w};
#pragma unroll
        for (int i = 0; i < 8; ++i)
#pragma unroll
            for (int j = 0; j < 8; ++j)
                acc[i][j] = __fadd_rn(acc[i][j], __fmul_rn(a[i], bb[j]));   // UNFUSED
    }

    float4 bv0 = *(const float4*)(biq + n0 + tx * 8);
    float4 bv1 = *(const float4*)(biq + n0 + tx * 8 + 4);
    const float bb[8] = {bv0.x, bv0.y, bv0.z, bv0.w, bv1.x, bv1.y, bv1.z, bv1.w};
#pragma unroll
    for (int i = 0; i < 8; ++i) {
        const int m = m0 + ty * 8 + i;
        if (m < Mc) {
            float o[8];
#pragma unroll
            for (int j = 0; j < 8; ++j) o[j] = __fadd_rn(acc[i][j], bb[j]);
            *(float4*)(Gx + (size_t)m * G4 + n0 + tx * 8)     = make_float4(o[0], o[1], o[2], o[3]);
            *(float4*)(Gx + (size_t)m * G4 + n0 + tx * 8 + 4) = make_float4(o[4], o[5], o[6], o[7]);
        }
    }
}

// ---------------------------------------------------------------------------
// Fused pipeline kernel, 256 blocks x 1024 threads:
//   blocks 0..63   : scan chunk k (reads Gx_rd)
//   blocks 64..255 : GEMM chunk k+1 (writes Gx_wr) — no intra-launch dependency
// All f32 arithmetic bit-identical to the passing r14 stack (GEMM: single
// accumulator per output, ascending k, unfused; scan ops unchanged).
// ---------------------------------------------------------------------------
__global__ __launch_bounds__(1024) void qlstm_fused(
    const float* __restrict__ Gx_rd, float* __restrict__ Gx_wr,
    const float* __restrict__ Xn, const float* __restrict__ Wq,
    const float* __restrict__ biq, int Mc_next,
    const int* __restrict__ whq4, const float* __restrict__ bhq,
    float* __restrict__ out, float* __restrict__ c_state, int* __restrict__ hq_state,
    float* __restrict__ hn, float* __restrict__ cn, int s0, int CHc) {
    const int t = threadIdx.x;

    __shared__ float Xs[IN_D][GPAD];          // gemm role (135KB with Ws)
    __shared__ float Ws[IN_D][GPAD];
    __shared__ __align__(16) int hq[2][64];   // scan role
    __shared__ float gl[G4];

    if (blockIdx.x < 64) {
        // ------------------------- scan role -------------------------
        const int b = blockIdx.x;

        const float bh = bhq[t];
        float creg = 0.0f;
        if (t < HID) creg = c_state[b * HID + t];
        if (t < 64)  hq[0][t] = hq_state[b * 64 + t];
        __syncthreads();

        float gx = Gx_rd[(size_t)b * G4 + t];

        for (int sl = 0; sl < CHc; ++sl) {
            const int p = sl & 1;
            float nx = 0.0f;
            if (sl + 1 < CHc) nx = Gx_rd[(size_t)((sl + 1) * BATCH + b) * G4 + t];

            // hh matvec row t: 16 coalesced dwordx4 weight loads + 64 sdot4,
            // 4 independent chains (integer-exact regrouping)
            const int4* __restrict__ wq = (const int4*)whq4;
            const int4* __restrict__ hv4 = (const int4*)hq[p];
            int ca0 = 0, ca1 = 0, ca2 = 0, ca3 = 0;
#pragma unroll
            for (int j = 0; j < 4; ++j) {
                const int4 wv = wq[j * 1024 + t];
                const int4 hv = hv4[j];
                ca0 = dot4i8(wv.x, hv.x, ca0);
                ca0 = dot4i8(wv.y, hv.y, ca0);
                ca0 = dot4i8(wv.z, hv.z, ca0);
                ca0 = dot4i8(wv.w, hv.w, ca0);
            }
#pragma unroll
            for (int j = 4; j < 8; ++j) {
                const int4 wv = wq[j * 1024 + t];
                const int4 hv = hv4[j];
                ca1 = dot4i8(wv.x, hv.x, ca1);
                ca1 = dot4i8(wv.y, hv.y, ca1);
                ca1 = dot4i8(wv.z, hv.z, ca1);
                ca1 = dot4i8(wv.w, hv.w, ca1);
            }
#pragma unroll
            for (int j = 8; j < 12; ++j) {
                const int4 wv = wq[j * 1024 + t];
                const int4 hv = hv4[j];
                ca2 = dot4i8(wv.x, hv.x, ca2);
                ca2 = dot4i8(wv.y, hv.y, ca2);
                ca2 = dot4i8(wv.z, hv.z, ca2);
                ca2 = dot4i8(wv.w, hv.w, ca2);
            }
#pragma unroll
            for (int j = 12; j < 16; ++j) {
                const int4 wv = wq[j * 1024 + t];
                const int4 hv = hv4[j];
                ca3 = dot4i8(wv.x, hv.x, ca3);
                ca3 = dot4i8(wv.y, hv.y, ca3);
                ca3 = dot4i8(wv.z, hv.z, ca3);
                ca3 = dot4i8(wv.w, hv.w, ca3);
            }
            const int acc = (ca0 + ca1) + (ca2 + ca3);

            const float hh = (float)acc * 0.00390625f;     // exact multiple of 2^-8
            const float gate = __fadd_rn(__fadd_rn(gx, hh), bh);

            float tv;                                      // wave-uniform branches
            if (t < 512)       tv = sig_vsl(gate);
            else if (t < 768)  tv = tanh_vsl(gate);
            else               tv = sig_vsl(gate);
            gl[t] = tv;
            __syncthreads();

            if (t < HID) {
                const float fv = gl[t + 256];
                const float gv = gl[t + 512];
                const float ov = gl[t + 768];
                const float cq = fminf(fmaxf(rintf(__fmul_rn(creg, 16.0f)), -128.0f), 127.0f) * 0.0625f;
                const float c1 = fmaf(fv, cq, __fmul_rn(tv, gv));   // contracted (r14)
                const float h1 = __fmul_rn(ov, tanh_vsl(c1));
                creg = c1;
                out[(size_t)((s0 + sl) * BATCH + b) * HID + t] = h1;
                const int hb = (int)fminf(fmaxf(rintf(__fmul_rn(h1, 16.0f)), -128.0f), 127.0f);
                ((signed char*)hq[p ^ 1])[t] = (signed char)hb;
                if (s0 + sl == S_LEN - 1) {
                    hn[b * HID + t] = h1;
                    cn[b * HID + t] = c1;
                }
            }
            __syncthreads();
            gx = nx;
        }

        if (t < 64)  hq_state[b * 64 + t] = hq[CHc & 1][t];
        if (t < HID) c_state[b * HID + t] = creg;
    } else if (Mc_next > 0) {
        // ------------------------- gemm role -------------------------
        const int wid = blockIdx.x - 64;                   // 0..191
        const int tiles_m = (Mc_next + 127) / 128;
        const int total = tiles_m * 8;
        const int tx = t & 31, ty = t >> 5;                // 32x32 thread grid

        for (int tile = wid; tile < total; tile += 192) {
            const int m0 = (tile >> 3) * 128;
            const int n0 = (tile & 7) * 128;

#pragma unroll
            for (int i = 0; i < 4; ++i) {
                const int flat = i * 1024 + t;             // 0..4095
                const int m  = flat >> 5;                  // 0..127
                const int k4 = flat & 31;
                float4 v = make_float4(0.f, 0.f, 0.f, 0.f);
                if (m0 + m < Mc_next) v = *(const float4*)(Xn + (size_t)(m0 + m) * IN_D + k4 * 4);
                Xs[k4 * 4 + 0][m] = v.x; Xs[k4 * 4 + 1][m] = v.y;
                Xs[k4 * 4 + 2][m] = v.z; Xs[k4 * 4 + 3][m] = v.w;
                float4 w = *(const float4*)(Wq + (size_t)(n0 + m) * IN_D + k4 * 4);
                Ws[k4 * 4 + 0][m] = w.x; Ws[k4 * 4 + 1][m] = w.y;
                Ws[k4 * 4 + 2][m] = w.z; Ws[k4 * 4 + 3][m] = w.w;
            }
            __syncthreads();

            float acc[4][4];
#pragma unroll
            for (int i = 0; i < 4; ++i)
#pragma unroll
                for (int j = 0; j < 4; ++j) acc[i][j] = 0.0f;

#pragma unroll 4
            for (int k = 0; k < IN_D; ++k) {
                float4 av = *(const float4*)&Xs[k][ty * 4];
                float4 bv = *(const float4*)&Ws[k][tx * 4];
                const float a[4]  = {av.x, av.y, av.z, av.w};
                const float bb[4] = {bv.x, bv.y, bv.z, bv.w};
#pragma unroll
                for (int i = 0; i < 4; ++i)
#pragma unroll
                    for (int j = 0; j < 4; ++j)
                        acc[i][j] = __fadd_rn(acc[i][j], __fmul_rn(a[i], bb[j]));  // UNFUSED
            }

            float4 bv = *(const float4*)(biq + n0 + tx * 4);
            const float bb[4] = {bv.x, bv.y, bv.z, bv.w};
#pragma unroll
            for (int i = 0; i < 4; ++i) {
                const int m = m0 + ty * 4 + i;
                if (m < Mc_next) {
                    float o[4];
#pragma unroll
                    for (int j = 0; j < 4; ++j) o[j] = __fadd_rn(acc[i][j], bb[j]);
                    *(float4*)(Gx_wr + (size_t)m * G4 + n0 + tx * 4) = make_float4(o[0], o[1], o[2], o[3]);
                }
            }
            __syncthreads();
        }
    }
}

// ---------------------------------------------------------------------------
// Host side: prep -> prologue GEMM(chunk0) -> fused launches (scan k || gemm k+1)
// ---------------------------------------------------------------------------
extern "C" void kernel_launch(void* const* d_in, const int* in_sizes, int n_in,
                              void* d_out, int out_size, void* d_ws, size_t ws_size,
                              hipStream_t stream) {
    (void)in_sizes; (void)n_in; (void)out_size;
    const float* x   = (const float*)d_in[0];
    const float* wih = (const float*)d_in[1];
    const float* whh = (const float*)d_in[2];
    const float* bih = (const float*)d_in[3];
    const float* bhh = (const float*)d_in[4];

    float* out = (float*)d_out;
    float* hn  = out + (size_t)S_LEN * BATCH * HID;
    float* cn  = hn + (size_t)BATCH * HID;

    char* ws = (char*)d_ws;
    const size_t off_wiq  = 0;                        // 524288
    const size_t off_biq  = off_wiq  + 524288;        // 4096
    const size_t off_bhq  = off_biq  + 4096;          // 4096
    const size_t off_c    = off_bhq  + 4096;          // 65536
    const size_t off_hq   = off_c    + 65536;         // 16384
    const size_t off_whq4 = off_hq   + 16384;         // 262144
    const size_t off_gx   = off_whq4 + 262144;

    float* wiq     = (float*)(ws + off_wiq);
    float* biq     = (float*)(ws + off_biq);
    float* bhq     = (float*)(ws + off_bhq);
    float* c_state = (float*)(ws + off_c);
    int*   hq_st   = (int*)  (ws + off_hq);
    int*   whq4    = (int*)  (ws + off_whq4);
    float* gxbase  = (float*)(ws + off_gx);

    const size_t per_step = (size_t)BATCH * G4 * 4;   // 256KB per time step
    size_t avail = (ws_size > off_gx) ? (ws_size - off_gx) : 0;
    int CH = (int)(avail / (2 * per_step));
    if (CH > 512) CH = 512;
    if (CH < 1) CH = 1;
    float* gxb[2] = { gxbase, gxbase + (size_t)CH * BATCH * G4 };

    qlstm_prep<<<512, 256, 0, stream>>>(wih, whh, bih, bhh, wiq, whq4, biq, bhq, c_state, hq_st);

    // prologue: GEMM chunk 0
    const int CHc0 = (S_LEN < CH) ? S_LEN : CH;
    const int Mc0  = CHc0 * BATCH;
    {
        dim3 grid((Mc0 + 127) / 128, G4 / 128);
        qlstm_gx<<<grid, 256, 0, stream>>>(x, wiq, biq, gxb[0], Mc0);
    }

    int k = 0;
    for (int s0 = 0; s0 < S_LEN; s0 += CH, ++k) {
        const int CHc = (S_LEN - s0 < CH) ? (S_LEN - s0) : CH;
        const int ns0 = s0 + CHc;
        const int Mc_next = (ns0 < S_LEN) ? (((S_LEN - ns0 < CH) ? (S_LEN - ns0) : CH) * BATCH) : 0;
        qlstm_fused<<<256, 1024, 0, stream>>>(
            gxb[k & 1], gxb[(k + 1) & 1],
            x + (size_t)ns0 * BATCH * IN_D, wiq, biq, Mc_next,
            whq4, bhq, out, c_state, hq_st, hn, cn, s0, CHc);
    }
}